// Round 10
// baseline (278.334 us; speedup 1.0000x reference)
//
#include <hip/hip_runtime.h>

#define NPTS 96
#define HID  64
#define RANK 32

typedef float f2 __attribute__((ext_vector_type(2)));

// ws layout (floats): trans[axis][n][f] = factor value, f contiguous, 128 B rows
#define TR(axis, n) ((((axis) * NPTS) + (n)) * RANK)

// -------- Kernel 1: the 4 tiny MLPs -> trans[axis][n][f] --------
__global__ __launch_bounds__(64) void spinn_mlp(
    const float* __restrict__ t, const float* __restrict__ x,
    const float* __restrict__ y, const float* __restrict__ z,
    const float* __restrict__ W1, const float* __restrict__ b1,
    const float* __restrict__ W2, const float* __restrict__ b2,
    const float* __restrict__ W3, const float* __restrict__ b3,
    float* __restrict__ ws)
{
    const int n    = blockIdx.x;   // point 0..95
    const int axis = blockIdx.y;   // 0..3
    const int j    = threadIdx.x;  // 0..63

    const float* coords[4] = { t, x, y, z };
    const float c = coords[axis][n];

    __shared__ float h1[HID];
    __shared__ float h2[HID];

    h1[j] = tanhf(fmaf(c, W1[axis * HID + j], b1[axis * HID + j]));
    __syncthreads();

    float a = b2[axis * HID + j];
    #pragma unroll
    for (int k = 0; k < HID; ++k)
        a = fmaf(h1[k], W2[(axis * HID + k) * HID + j], a);
    h2[j] = tanhf(a);
    __syncthreads();

    if (j < RANK) {
        float o = b3[axis * RANK + j];
        #pragma unroll
        for (int k = 0; k < HID; ++k)
            o = fmaf(h2[k], W3[(axis * HID + k) * RANK + j], o);
        ws[TR(axis, n) + j] = o;   // trans [axis][n][f]
    }
}

// -------- Kernel 2: reconstruction with SEQUENTIAL per-block stores --------
// Block = (t,x): writes out[t,x,:,:] = 36 KB fully contiguous (fill-like
// stream, DRAM-page friendly). 384 threads: thread = (y8 = tid/48, zp = tid%48),
// z = 2*zp. Register state: q2[k][zz] = (fz[2k,z+zz], fz[2k+1,z+zz]);
// A2[k] = (ft[2k]*fx[2k], ft[2k+1]*fx[2k+1]) block-uniform.
// Per y-iteration (12 of them, 8 y each): g2 = A2*fy2 (16 pk-mul),
// acc[zz] += g2[k]*q2[k][zz] (32 pk-fma), out = horizontal sums (f2 store).
__global__ __launch_bounds__(384, 3) void spinn_recon(
    const float* __restrict__ ws, float* __restrict__ out)
{
    const int xx  = blockIdx.x;        // x: 0..95
    const int tt  = blockIdx.y;        // t: 0..95
    const int tid = threadIdx.x;       // 0..383
    const int y8  = tid / 48;          // 0..7
    const int zp  = tid % 48;          // z pair
    const int z0  = zp * 2;

    const float* ftR = ws + TR(0, tt);
    const float* fxR = ws + TR(1, xx);
    const float* fzR0 = ws + TR(3, z0);
    const float* fzR1 = ws + TR(3, z0 + 1);

    // Block-uniform A2[k] = ft2 * fx2  (16 pk-mul)
    f2 A2[16];
    #pragma unroll
    for (int k = 0; k < 16; ++k)
        A2[k] = *(const f2*)(ftR + 2 * k) * *(const f2*)(fxR + 2 * k);

    // Thread-resident fz pairs: q2[k][zz]
    f2 q2[16][2];
    #pragma unroll
    for (int k = 0; k < 16; ++k) {
        q2[k][0] = *(const f2*)(fzR0 + 2 * k);
        q2[k][1] = *(const f2*)(fzR1 + 2 * k);
    }

    float* outb = out + ((size_t)tt * NPTS + xx) * (NPTS * NPTS) + z0;

    #pragma unroll 1
    for (int yb = 0; yb < 12; ++yb) {
        const int yy = yb * 8 + y8;
        const float* fyR = ws + TR(2, yy);   // 128 B, shared by 48 threads

        f2 a0 = { 0.f, 0.f }, a1 = { 0.f, 0.f };
        #pragma unroll
        for (int k = 0; k < 16; ++k) {
            const f2 g2 = A2[k] * *(const f2*)(fyR + 2 * k);  // pk-mul
            a0 = __builtin_elementwise_fma(g2, q2[k][0], a0);
            a1 = __builtin_elementwise_fma(g2, q2[k][1], a1);
        }
        const f2 r = { a0.x + a0.y, a1.x + a1.y };
        *(f2*)(outb + (size_t)yy * NPTS) = r;   // block writes 3 KB contig/iter
    }
}

extern "C" void kernel_launch(void* const* d_in, const int* in_sizes, int n_in,
                              void* d_out, int out_size, void* d_ws, size_t ws_size,
                              hipStream_t stream)
{
    const float* t  = (const float*)d_in[0];
    const float* x  = (const float*)d_in[1];
    const float* y  = (const float*)d_in[2];
    const float* z  = (const float*)d_in[3];
    const float* W1 = (const float*)d_in[4];
    const float* b1 = (const float*)d_in[5];
    const float* W2 = (const float*)d_in[6];
    const float* b2 = (const float*)d_in[7];
    const float* W3 = (const float*)d_in[8];
    const float* b3 = (const float*)d_in[9];

    float* ws  = (float*)d_ws;
    float* out = (float*)d_out;

    spinn_mlp<<<dim3(NPTS, 4), 64, 0, stream>>>(t, x, y, z, W1, b1, W2, b2, W3, b3, ws);
    spinn_recon<<<dim3(NPTS, NPTS), 384, 0, stream>>>(ws, out);
}

// Round 11
// 109.706 us; speedup vs baseline: 2.5371x; 2.5371x over previous
//
#include <hip/hip_runtime.h>

#define NPTS 96
#define HID  64
#define RANK 32

typedef float f2 __attribute__((ext_vector_type(2)));

// ws layout (floats): trans[axis][n][f], f contiguous (128 B rows)
#define TR(axis, n) ((((axis) * NPTS) + (n)) * RANK)

// -------- Kernel 1: the 4 tiny MLPs -> trans[axis][n][f] --------
__global__ __launch_bounds__(64) void spinn_mlp(
    const float* __restrict__ t, const float* __restrict__ x,
    const float* __restrict__ y, const float* __restrict__ z,
    const float* __restrict__ W1, const float* __restrict__ b1,
    const float* __restrict__ W2, const float* __restrict__ b2,
    const float* __restrict__ W3, const float* __restrict__ b3,
    float* __restrict__ ws)
{
    const int n    = blockIdx.x;   // point 0..95
    const int axis = blockIdx.y;   // 0..3
    const int j    = threadIdx.x;  // 0..63

    const float* coords[4] = { t, x, y, z };
    const float c = coords[axis][n];

    __shared__ float h1[HID];
    __shared__ float h2[HID];

    h1[j] = tanhf(fmaf(c, W1[axis * HID + j], b1[axis * HID + j]));
    __syncthreads();

    float a = b2[axis * HID + j];
    #pragma unroll
    for (int k = 0; k < HID; ++k)
        a = fmaf(h1[k], W2[(axis * HID + k) * HID + j], a);
    h2[j] = tanhf(a);
    __syncthreads();

    if (j < RANK) {
        float o = b3[axis * RANK + j];
        #pragma unroll
        for (int k = 0; k < HID; ++k)
            o = fmaf(h2[k], W3[(axis * HID + k) * RANK + j], o);
        ws[TR(axis, n) + j] = o;   // trans [axis][n][f]
    }
}

// -------- Kernel 2: R6 structure + LDS-staged fx (single change) --------
// Thread owns (y, 2 consecutive z); q2[k][zz] = (ft*fy ⊙ fz-pairs) in 64 VGPRs.
// Block's 24 fx rows staged to LDS once; steady-state loop = LDS broadcast
// reads + 32 pk-fma + one f2 store. Stores are the ONLY global ops in flight.
__global__ __launch_bounds__(192, 4) void spinn_recon(
    const float* __restrict__ ws, float* __restrict__ out)
{
    const int tt  = blockIdx.x;        // t: 0..95
    const int yb  = blockIdx.y;        // y block: 0..23 (4 y each)
    const int xq  = blockIdx.z;        // x quarter: 0..3 (24 x each)
    const int tid = threadIdx.x;       // 0..191
    const int zp  = tid % 48;          // z pair index
    const int yq  = tid / 48;          // 0..3
    const int yy  = yb * 4 + yq;
    const int z0  = zp * 2;
    const int x0  = xq * 24;

    __shared__ float fxs[24 * RANK];   // 3 KB: this block's fx rows
    for (int i = tid; i < 24 * RANK; i += 192)
        fxs[i] = ws[TR(1, x0) + i];    // rows x0..x0+23, coalesced

    const float* ftT = ws + TR(0, tt);
    const float* fyT = ws + TR(2, yy);
    const float* fzP = ws + TR(3, 0);  // fz[n][f] rows

    // q2[k][zz] = ( g0*fz[z0+zz][2k], g1*fz[z0+zz][2k+1] ), g = ft*fy
    f2 q2[16][2];
    #pragma unroll
    for (int k = 0; k < 16; ++k) {
        const f2 ft2 = *(const f2*)(ftT + 2 * k);
        const f2 fy2 = *(const f2*)(fyT + 2 * k);
        const f2 g   = ft2 * fy2;
        const f2 za  = *(const f2*)(fzP + (size_t)z0 * RANK + 2 * k);       // fz row z0
        const f2 zb  = *(const f2*)(fzP + (size_t)(z0 + 1) * RANK + 2 * k); // fz row z0+1
        q2[k][0] = f2{ g.x * za.x, g.y * za.y };
        q2[k][1] = f2{ g.x * zb.x, g.y * zb.y };
    }
    __syncthreads();

    float* outp = out + (size_t)tt * NPTS * NPTS * NPTS
                      + (size_t)x0 * NPTS * NPTS
                      + (size_t)yy * NPTS + z0;

    #pragma unroll 2
    for (int xs = 0; xs < 24; ++xs) {
        const f2* fp = (const f2*)(fxs + xs * RANK);  // LDS broadcast reads
        f2 a0 = { 0.f, 0.f }, a1 = { 0.f, 0.f };
        #pragma unroll
        for (int k = 0; k < 16; ++k) {
            const f2 p = fp[k];                       // (fx[2k], fx[2k+1])
            a0 = __builtin_elementwise_fma(p, q2[k][0], a0);
            a1 = __builtin_elementwise_fma(p, q2[k][1], a1);
        }
        const f2 r = { a0.x + a0.y, a1.x + a1.y };
        *(f2*)outp = r;
        outp += NPTS * NPTS;
    }
}

extern "C" void kernel_launch(void* const* d_in, const int* in_sizes, int n_in,
                              void* d_out, int out_size, void* d_ws, size_t ws_size,
                              hipStream_t stream)
{
    const float* t  = (const float*)d_in[0];
    const float* x  = (const float*)d_in[1];
    const float* y  = (const float*)d_in[2];
    const float* z  = (const float*)d_in[3];
    const float* W1 = (const float*)d_in[4];
    const float* b1 = (const float*)d_in[5];
    const float* W2 = (const float*)d_in[6];
    const float* b2 = (const float*)d_in[7];
    const float* W3 = (const float*)d_in[8];
    const float* b3 = (const float*)d_in[9];

    float* ws  = (float*)d_ws;
    float* out = (float*)d_out;

    spinn_mlp<<<dim3(NPTS, 4), 64, 0, stream>>>(t, x, y, z, W1, b1, W2, b2, W3, b3, ws);
    spinn_recon<<<dim3(NPTS, 24, 4), 192, 0, stream>>>(ws, out);
}